// Round 14
// baseline (192.002 us; speedup 1.0000x reference)
//
#include <hip/hip_runtime.h>

#define N_NODES 50000
#define N_REL 16
#define N_BASIS 8
#define N_EDGES 800000
#define G1_BLOCKS 782     // ceil(50000/64)
#define SC_BLOCKS 3125    // ceil(800000/256)
#define WREL_BLOCKS 340   // (17*4096+17*1024)/256
#define ZERO_BLOCKS 391   // ceil(100000 int4 / 256)  (8 partitions x 50000 cursors)
#define NPART 8           // scatter partitions (heuristic: blockIdx & 7 ~ XCD id)
#define CAPP 16           // per-partition bucket cap; deg/part ~ Poisson(2), P(>16) ~ 5e-11

typedef short s8v __attribute__((ext_vector_type(8)));    // 8 bf16 MFMA A/B frag
typedef float f4v __attribute__((ext_vector_type(4)));    // 4 fp32 MFMA C/D frag

__device__ inline unsigned short f2bf(float f) {
    union { float f; unsigned u; } v; v.f = f;
    unsigned r = (v.u + 0x7FFFu + ((v.u >> 16) & 1u)) >> 16;   // RNE
    return (unsigned short)r;
}
__device__ inline float bf2f(unsigned short b) {
    union { unsigned u; float f; } v; v.u = ((unsigned)b) << 16;
    return v.f;
}
// a[0..7] += inv * (8 bf16 packed in int4)
__device__ __forceinline__ void acc8(float* a, float inv, int4 p) {
    a[0] += inv * __int_as_float((int)((unsigned)p.x << 16));
    a[1] += inv * __int_as_float(p.x & (int)0xFFFF0000u);
    a[2] += inv * __int_as_float((int)((unsigned)p.y << 16));
    a[3] += inv * __int_as_float(p.y & (int)0xFFFF0000u);
    a[4] += inv * __int_as_float((int)((unsigned)p.z << 16));
    a[5] += inv * __int_as_float(p.z & (int)0xFFFF0000u);
    a[6] += inv * __int_as_float((int)((unsigned)p.w << 16));
    a[7] += inv * __int_as_float(p.w & (int)0xFFFF0000u);
}

// ---- pre-pass: wrel (blocks 0..339) || cursor zero (rest) ----
__global__ __launch_bounds__(256) void k_pre(const float* __restrict__ b1, const float* __restrict__ c1,
                                             const float* __restrict__ s1f,
                                             const float* __restrict__ b2, const float* __restrict__ c2,
                                             const float* __restrict__ s2f,
                                             unsigned short* __restrict__ w1T,
                                             unsigned short* __restrict__ w2T,
                                             int* __restrict__ cursor) {
    int bid = blockIdx.x;
    if (bid >= WREL_BLOCKS) {
        int i = (bid - WREL_BLOCKS) * 256 + threadIdx.x;
        if (i < 100000) ((int4*)cursor)[i] = make_int4(0, 0, 0, 0);
        return;
    }
    int idx = bid * 256 + threadIdx.x;
    if (idx < 17 * 4096) {
        int r = idx >> 12, o = (idx >> 6) & 63, k = idx & 63;
        float acc = 0.f;
        if (r < 16) {
            #pragma unroll
            for (int b = 0; b < N_BASIS; b++) acc += c1[r * N_BASIS + b] * b1[b * 4096 + k * 64 + o];
        } else {
            acc = s1f[k * 64 + o];
        }
        w1T[idx] = f2bf(acc);
    } else {
        int idx2 = idx - 17 * 4096;
        if (idx2 < 17 * 1024) {
            int r = idx2 >> 10, o = (idx2 >> 6) & 15, k = idx2 & 63;
            float acc = 0.f;
            if (r < 16) {
                #pragma unroll
                for (int b = 0; b < N_BASIS; b++) acc += c2[r * N_BASIS + b] * b2[b * 1024 + k * 16 + o];
            } else {
                acc = s2f[k * 16 + o];
            }
            w2T[idx2] = f2bf(acc);
        }
    }
}

// ---- gemm1 tile body (R10-proven): LDS-dbuf weights + contiguous-store epilogue ----
__device__ __forceinline__ void gemm1_tile(int tile, int tid,
                                           const float* __restrict__ x,
                                           const unsigned short* __restrict__ w1T,
                                           unsigned short* __restrict__ t1,
                                           unsigned short* __restrict__ h,
                                           unsigned short* wbuf,    // 2*4096 shorts
                                           unsigned short* ou) {    // 4*1024 shorts
    int wv = tid >> 6, lane = tid & 63;
    int m = lane & 15, q = lane >> 4;
    int nb = tile * 64 + wv * 16;
    bool active = (nb < N_NODES);
    int n = active ? (nb + m) : 0;

    const float* xr = x + (size_t)n * 64 + q * 8;
    float4 x0a = *(const float4*)(xr);
    float4 x0b = *(const float4*)(xr + 4);
    float4 x1a = *(const float4*)(xr + 32);
    float4 x1b = *(const float4*)(xr + 36);
    s8v b0, b1;
    b0[0] = f2bf(x0a.x); b0[1] = f2bf(x0a.y); b0[2] = f2bf(x0a.z); b0[3] = f2bf(x0a.w);
    b0[4] = f2bf(x0b.x); b0[5] = f2bf(x0b.y); b0[6] = f2bf(x0b.z); b0[7] = f2bf(x0b.w);
    b1[0] = f2bf(x1a.x); b1[1] = f2bf(x1a.y); b1[2] = f2bf(x1a.z); b1[3] = f2bf(x1a.w);
    b1[4] = f2bf(x1b.x); b1[5] = f2bf(x1b.y); b1[6] = f2bf(x1b.z); b1[7] = f2bf(x1b.w);

    int c0 = tid, c1 = tid + 256;
    int p0s = (c0 >> 3) * 64 + (((c0 & 7) ^ ((c0 >> 3) & 7)) << 3);
    int p1s = (c1 >> 3) * 64 + (((c1 & 7) ^ ((c1 >> 3) & 7)) << 3);

    {
        const int4* src = (const int4*)w1T;
        int4 v0 = src[c0], v1 = src[c1];
        *(int4*)&wbuf[p0s] = v0;
        *(int4*)&wbuf[p1s] = v1;
    }
    __syncthreads();

    for (int w = 0; w < 17; w++) {
        int cur = w & 1;
        if (w < 16) {
            const int4* src = (const int4*)w1T + (w + 1) * 512;
            int4 v0 = src[c0], v1 = src[c1];
            *(int4*)&wbuf[(cur ^ 1) * 4096 + p0s] = v0;
            *(int4*)&wbuf[(cur ^ 1) * 4096 + p1s] = v1;
        }
        #pragma unroll
        for (int ct = 0; ct < 4; ct++) {
            int ro = ct * 16 + m;
            int pa = q ^ (ro & 7);
            int pb = (4 + q) ^ (ro & 7);
            s8v A0 = *(const s8v*)&wbuf[cur * 4096 + ro * 64 + pa * 8];
            s8v A1 = *(const s8v*)&wbuf[cur * 4096 + ro * 64 + pb * 8];
            f4v acc = (f4v){0.f, 0.f, 0.f, 0.f};
            acc = __builtin_amdgcn_mfma_f32_16x16x32_bf16(A0, b0, acc, 0, 0, 0);
            acc = __builtin_amdgcn_mfma_f32_16x16x32_bf16(A1, b1, acc, 0, 0, 0);
            ushort4 o4;
            o4.x = f2bf(acc[0]); o4.y = f2bf(acc[1]); o4.z = f2bf(acc[2]); o4.w = f2bf(acc[3]);
            int g = ct * 2 + (q >> 1);
            int pg = g ^ (m & 7);
            *(ushort4*)&ou[wv * 1024 + m * 64 + pg * 8 + (q & 1) * 4] = o4;
        }
        if (active) {
            int r1 = lane >> 3, g1 = lane & 7;
            int pg1 = g1 ^ (r1 & 7);
            int4 d0 = *(const int4*)&ou[wv * 1024 + r1 * 64 + pg1 * 8];
            int4 d1 = *(const int4*)&ou[wv * 1024 + (r1 + 8) * 64 + pg1 * 8];
            unsigned short* base = (w < 16) ? (t1 + ((size_t)w * N_NODES + nb) * 64)
                                            : (h + (size_t)nb * 64);
            *(int4*)(base + lane * 8) = d0;
            *(int4*)(base + 512 + lane * 8) = d1;
        }
        __syncthreads();
    }
}

// ---- FUSED: gemm1 (blocks 0..781) || XCD-partitioned bucket scatter (rest) ----
__global__ __launch_bounds__(256) void k_fused1(const float* __restrict__ x,
                                                const unsigned short* __restrict__ w1T,
                                                unsigned short* __restrict__ t1,
                                                unsigned short* __restrict__ h,
                                                const int* __restrict__ ei,
                                                const int* __restrict__ et,
                                                int* __restrict__ cursor,
                                                int* __restrict__ sed) {
    __shared__ __align__(16) unsigned short wbuf[2 * 4096];
    __shared__ __align__(16) unsigned short ou[4 * 1024];
    if (blockIdx.x >= G1_BLOCKS) {
        int e = (blockIdx.x - G1_BLOCKS) * 256 + threadIdx.x;
        int p = blockIdx.x & 7;    // heuristic: global block id % 8 ~ XCD -> L2-local bucket lines
        if (e < N_EDGES) {
            int src = ei[e];
            int dst = ei[N_EDGES + e];
            int t = et[e];
            int pos = atomicAdd(&cursor[p * N_NODES + dst], 1);
            if (pos < CAPP) sed[p * (N_NODES * CAPP) + dst * CAPP + pos] = (t << 16) | src;
        }
        return;
    }
    gemm1_tile(blockIdx.x, threadIdx.x, x, w1T, t1, h, wbuf, ou);
}

// ---- concat 8 partition buckets of node n into wave-private LDS ent[]; returns deg ----
// lane layout for staging: p = lane>>3, j = lane&7 (covers entries j and j+8).
__device__ __forceinline__ int stage_node(int n, int lane,
                                          const int* __restrict__ cursor,
                                          const int* __restrict__ sed,
                                          int* ent) {
    int dp = 0;
    if (lane < NPART) {
        dp = cursor[lane * N_NODES + n];
        dp = dp < CAPP ? dp : CAPP;
    }
    int p = lane >> 3, j = lane & 7;
    int off = 0, deg = 0, mydeg = 0;
    #pragma unroll
    for (int q = 0; q < NPART; q++) {
        int dq = __shfl(dp, q, 64);
        if (q < p) off += dq;
        if (q == p) mydeg = dq;
        deg += dq;
    }
    const int* bucket = sed + p * (N_NODES * CAPP) + n * CAPP;
    if (j < mydeg) ent[off + j] = bucket[j];
    if (j + 8 < mydeg) ent[off + j + 8] = bucket[j + 8];
    return deg;
}

// ---- layer-1 aggregation: wave/node, LDS concat + hist, 8 slots x unroll-2 ----
__global__ __launch_bounds__(256) void k_agg1(const int* __restrict__ cursor,
                                              const int* __restrict__ sed,
                                              const unsigned short* __restrict__ t1,
                                              unsigned short* __restrict__ h) {
    __shared__ int ent[4][128];
    __shared__ int hist[4][16];
    int tid = threadIdx.x;
    int wv = tid >> 6, lane = tid & 63;
    int n = blockIdx.x * 4 + wv;          // 12500*4 = 50000 exact

    if (lane < 16) hist[wv][lane] = 0;
    int deg = stage_node(n, lane, cursor, sed, ent[wv]);
    if (lane < deg) atomicAdd(&hist[wv][ent[wv][lane] >> 16], 1);
    if (lane + 64 < deg) atomicAdd(&hist[wv][ent[wv][lane + 64] >> 16], 1);
    // wave-private LDS: in-order within wave, no barrier needed

    int slot = lane >> 3;     // edge slot 0..7
    int d8 = lane & 7;        // dim group: 8 bf16
    float a[8];
    #pragma unroll
    for (int j = 0; j < 8; j++) a[j] = 0.f;
    for (int i = slot; i < deg; i += 16) {
        int e0 = ent[wv][i];
        bool has1 = (i + 8) < deg;
        int e1 = has1 ? ent[wv][i + 8] : e0;
        int t0 = e0 >> 16, s0 = e0 & 0xFFFF;
        int t1i = e1 >> 16, s1 = e1 & 0xFFFF;
        float inv0 = 1.0f / (float)hist[wv][t0];
        float inv1 = has1 ? (1.0f / (float)hist[wv][t1i]) : 0.f;
        int4 p0 = *(const int4*)(t1 + ((size_t)(t0 * N_NODES + s0)) * 64 + d8 * 8);
        int4 p1 = *(const int4*)(t1 + ((size_t)(t1i * N_NODES + s1)) * 64 + d8 * 8);
        acc8(a, inv0, p0);
        acc8(a, inv1, p1);
    }
    #pragma unroll
    for (int j = 0; j < 8; j++) {
        a[j] += __shfl_xor(a[j], 8, 64);
        a[j] += __shfl_xor(a[j], 16, 64);
        a[j] += __shfl_xor(a[j], 32, 64);
    }
    if (slot == 0) {
        size_t hi = (size_t)n * 64 + d8 * 8;
        int4 hv = *(const int4*)(h + hi);
        float b[8];
        b[0] = __int_as_float((int)((unsigned)hv.x << 16));
        b[1] = __int_as_float(hv.x & (int)0xFFFF0000u);
        b[2] = __int_as_float((int)((unsigned)hv.y << 16));
        b[3] = __int_as_float(hv.y & (int)0xFFFF0000u);
        b[4] = __int_as_float((int)((unsigned)hv.z << 16));
        b[5] = __int_as_float(hv.z & (int)0xFFFF0000u);
        b[6] = __int_as_float((int)((unsigned)hv.w << 16));
        b[7] = __int_as_float(hv.w & (int)0xFFFF0000u);
        ushort4 o0, o1;
        o0.x = f2bf(b[0] + a[0]); o0.y = f2bf(b[1] + a[1]);
        o0.z = f2bf(b[2] + a[2]); o0.w = f2bf(b[3] + a[3]);
        o1.x = f2bf(b[4] + a[4]); o1.y = f2bf(b[5] + a[5]);
        o1.z = f2bf(b[6] + a[6]); o1.w = f2bf(b[7] + a[7]);
        *(ushort4*)(h + hi) = o0;
        *(ushort4*)(h + hi + 4) = o1;
    }
}

// ---- layer-2 MFMA transform: all weights staged in LDS once (R10-proven) ----
__global__ __launch_bounds__(256) void k_gemm2(const unsigned short* __restrict__ h,
                                               const unsigned short* __restrict__ w2T,
                                               unsigned short* __restrict__ t2, float* __restrict__ out) {
    __shared__ __align__(16) unsigned short wall[272 * 64];
    int tid = threadIdx.x;
    int wv = tid >> 6, lane = tid & 63;
    int m = lane & 15, q = lane >> 4;
    int nb = blockIdx.x * 64 + wv * 16;

    for (int c = tid; c < 2176; c += 256) {
        int4 v = ((const int4*)w2T)[c];
        int row = c >> 3, g = c & 7;
        *(int4*)&wall[row * 64 + ((g ^ (row & 7)) << 3)] = v;
    }
    __syncthreads();
    if (nb >= N_NODES) return;
    int n = nb + m;

    s8v b0 = *(const s8v*)(h + (size_t)n * 64 + q * 8);
    s8v b1 = *(const s8v*)(h + (size_t)n * 64 + 32 + q * 8);
    #pragma unroll
    for (int j = 0; j < 8; j++) {
        if ((unsigned short)b0[j] & 0x8000u) b0[j] = 0;
        if ((unsigned short)b1[j] & 0x8000u) b1[j] = 0;
    }

    for (int w = 0; w < 17; w++) {
        int ro = w * 16 + m;
        int pa = q ^ (ro & 7);
        int pb = (4 + q) ^ (ro & 7);
        s8v A0 = *(const s8v*)&wall[ro * 64 + pa * 8];
        s8v A1 = *(const s8v*)&wall[ro * 64 + pb * 8];
        f4v acc = (f4v){0.f, 0.f, 0.f, 0.f};
        acc = __builtin_amdgcn_mfma_f32_16x16x32_bf16(A0, b0, acc, 0, 0, 0);
        acc = __builtin_amdgcn_mfma_f32_16x16x32_bf16(A1, b1, acc, 0, 0, 0);
        if (w < 16) {
            ushort4 o;
            o.x = f2bf(acc[0]); o.y = f2bf(acc[1]); o.z = f2bf(acc[2]); o.w = f2bf(acc[3]);
            *(ushort4*)(t2 + ((size_t)w * N_NODES + n) * 16 + q * 4) = o;
        } else {
            *(float4*)(out + (size_t)n * 16 + q * 4) = make_float4(acc[0], acc[1], acc[2], acc[3]);
        }
    }
}

// ---- layer-2 aggregation: wave/node, LDS concat + hist, 16 slots x unroll-2 ----
__global__ __launch_bounds__(256) void k_agg2(const int* __restrict__ cursor,
                                              const int* __restrict__ sed,
                                              const unsigned short* __restrict__ t2,
                                              float* __restrict__ out) {
    __shared__ int ent[4][128];
    __shared__ int hist[4][16];
    int tid = threadIdx.x;
    int wv = tid >> 6, lane = tid & 63;
    int n = blockIdx.x * 4 + wv;

    if (lane < 16) hist[wv][lane] = 0;
    int deg = stage_node(n, lane, cursor, sed, ent[wv]);
    if (lane < deg) atomicAdd(&hist[wv][ent[wv][lane] >> 16], 1);
    if (lane + 64 < deg) atomicAdd(&hist[wv][ent[wv][lane + 64] >> 16], 1);

    int slot = lane >> 2;     // edge slot 0..15
    int d4 = lane & 3;        // dim group: 4 bf16
    float a[4] = {0.f, 0.f, 0.f, 0.f};
    for (int i = slot; i < deg; i += 32) {
        int e0 = ent[wv][i];
        bool has1 = (i + 16) < deg;
        int e1 = has1 ? ent[wv][i + 16] : e0;
        int t0 = e0 >> 16, s0 = e0 & 0xFFFF;
        int t1i = e1 >> 16, s1 = e1 & 0xFFFF;
        float inv0 = 1.0f / (float)hist[wv][t0];
        float inv1 = has1 ? (1.0f / (float)hist[wv][t1i]) : 0.f;
        ushort4 v0 = *(const ushort4*)(t2 + ((size_t)(t0 * N_NODES + s0)) * 16 + d4 * 4);
        ushort4 v1 = *(const ushort4*)(t2 + ((size_t)(t1i * N_NODES + s1)) * 16 + d4 * 4);
        a[0] += inv0 * bf2f(v0.x) + inv1 * bf2f(v1.x);
        a[1] += inv0 * bf2f(v0.y) + inv1 * bf2f(v1.y);
        a[2] += inv0 * bf2f(v0.z) + inv1 * bf2f(v1.z);
        a[3] += inv0 * bf2f(v0.w) + inv1 * bf2f(v1.w);
    }
    #pragma unroll
    for (int k = 0; k < 4; k++) {
        a[k] += __shfl_xor(a[k], 4, 64);
        a[k] += __shfl_xor(a[k], 8, 64);
        a[k] += __shfl_xor(a[k], 16, 64);
        a[k] += __shfl_xor(a[k], 32, 64);
    }
    if (slot == 0) {
        float* p = out + (size_t)n * 16 + d4 * 4;
        float4 c = *(const float4*)p;
        c.x += a[0]; c.y += a[1]; c.z += a[2]; c.w += a[3];
        *(float4*)p = c;
    }
}

extern "C" void kernel_launch(void* const* d_in, const int* in_sizes, int n_in,
                              void* d_out, int out_size, void* d_ws, size_t ws_size,
                              hipStream_t stream) {
    const float* x      = (const float*)d_in[0];
    const float* bases1 = (const float*)d_in[1];
    const float* coeffs1= (const float*)d_in[2];
    const float* self1  = (const float*)d_in[3];
    const float* bases2 = (const float*)d_in[4];
    const float* coeffs2= (const float*)d_in[5];
    const float* self2  = (const float*)d_in[6];
    const int*   ei     = (const int*)d_in[7];
    const int*   et     = (const int*)d_in[8];
    float* out = (float*)d_out;

    char* ws = (char*)d_ws;
    int*            cursor = (int*)(ws + 0);                    //   1,600,000 (8 x 50000)
    unsigned short* w1T    = (unsigned short*)(ws + 1600000);   //     139,264
    unsigned short* w2T    = (unsigned short*)(ws + 1739264);   //      34,816
    int*            sed    = (int*)(ws + 1774080);              //  25,600,000 (8 x 50000 x 16 x 4B)
    unsigned short* h      = (unsigned short*)(ws + 27374080);  //   6,400,000
    unsigned short* t1     = (unsigned short*)(ws + 33774080);  // 102,400,000 -> 136,174,080
    unsigned short* t2     = (unsigned short*)(ws + 136174080); //  25,600,000 -> 161,774,080

    k_pre<<<WREL_BLOCKS + ZERO_BLOCKS, 256, 0, stream>>>(
        bases1, coeffs1, self1, bases2, coeffs2, self2, w1T, w2T, cursor);
    k_fused1<<<G1_BLOCKS + SC_BLOCKS, 256, 0, stream>>>(x, w1T, t1, h, ei, et, cursor, sed);
    k_agg1<<<12500, 256, 0, stream>>>(cursor, sed, t1, h);
    k_gemm2<<<G1_BLOCKS, 256, 0, stream>>>(h, w2T, t2, out);
    k_agg2<<<12500, 256, 0, stream>>>(cursor, sed, t2, out);
}

// Round 15
// 181.945 us; speedup vs baseline: 1.0553x; 1.0553x over previous
//
#include <hip/hip_runtime.h>

#define N_NODES 50000
#define N_REL 16
#define N_BASIS 8
#define N_EDGES 800000
#define G1_BLOCKS 782     // ceil(50000/64)
#define SC_BLOCKS 3125    // ceil(800000/256)
#define WREL_BLOCKS 340   // (17*4096+17*1024)/256
#define ZERO_BLOCKS 49    // ceil(12504 int4 / 256)
#define CAP 64            // bucket capacity; deg ~ Poisson(16), P(>64) ~ 1e-19

typedef short s8v __attribute__((ext_vector_type(8)));    // 8 bf16 MFMA A/B frag
typedef float f4v __attribute__((ext_vector_type(4)));    // 4 fp32 MFMA C/D frag

__device__ inline unsigned short f2bf(float f) {
    union { float f; unsigned u; } v; v.f = f;
    unsigned r = (v.u + 0x7FFFu + ((v.u >> 16) & 1u)) >> 16;   // RNE
    return (unsigned short)r;
}
__device__ inline float bf2f(unsigned short b) {
    union { unsigned u; float f; } v; v.u = ((unsigned)b) << 16;
    return v.f;
}
// a[0..7] += inv * (8 bf16 packed in int4)
__device__ __forceinline__ void acc8(float* a, float inv, int4 p) {
    a[0] += inv * __int_as_float((int)((unsigned)p.x << 16));
    a[1] += inv * __int_as_float(p.x & (int)0xFFFF0000u);
    a[2] += inv * __int_as_float((int)((unsigned)p.y << 16));
    a[3] += inv * __int_as_float(p.y & (int)0xFFFF0000u);
    a[4] += inv * __int_as_float((int)((unsigned)p.z << 16));
    a[5] += inv * __int_as_float(p.z & (int)0xFFFF0000u);
    a[6] += inv * __int_as_float((int)((unsigned)p.w << 16));
    a[7] += inv * __int_as_float(p.w & (int)0xFFFF0000u);
}

// ---- pre-pass: wrel (blocks 0..339) || cursor zero (rest) ----
__global__ __launch_bounds__(256) void k_pre(const float* __restrict__ b1, const float* __restrict__ c1,
                                             const float* __restrict__ s1f,
                                             const float* __restrict__ b2, const float* __restrict__ c2,
                                             const float* __restrict__ s2f,
                                             unsigned short* __restrict__ w1T,
                                             unsigned short* __restrict__ w2T,
                                             int* __restrict__ cursor) {
    int bid = blockIdx.x;
    if (bid >= WREL_BLOCKS) {
        int i = (bid - WREL_BLOCKS) * 256 + threadIdx.x;
        if (i < 12504) ((int4*)cursor)[i] = make_int4(0, 0, 0, 0);
        return;
    }
    int idx = bid * 256 + threadIdx.x;
    if (idx < 17 * 4096) {
        int r = idx >> 12, o = (idx >> 6) & 63, k = idx & 63;
        float acc = 0.f;
        if (r < 16) {
            #pragma unroll
            for (int b = 0; b < N_BASIS; b++) acc += c1[r * N_BASIS + b] * b1[b * 4096 + k * 64 + o];
        } else {
            acc = s1f[k * 64 + o];
        }
        w1T[idx] = f2bf(acc);
    } else {
        int idx2 = idx - 17 * 4096;
        if (idx2 < 17 * 1024) {
            int r = idx2 >> 10, o = (idx2 >> 6) & 15, k = idx2 & 63;
            float acc = 0.f;
            if (r < 16) {
                #pragma unroll
                for (int b = 0; b < N_BASIS; b++) acc += c2[r * N_BASIS + b] * b2[b * 1024 + k * 16 + o];
            } else {
                acc = s2f[k * 16 + o];
            }
            w2T[idx2] = f2bf(acc);
        }
    }
}

// ---- gemm1 tile body (R10-proven): LDS-dbuf weights + contiguous-store epilogue ----
__device__ __forceinline__ void gemm1_tile(int tile, int tid,
                                           const float* __restrict__ x,
                                           const unsigned short* __restrict__ w1T,
                                           unsigned short* __restrict__ t1,
                                           unsigned short* __restrict__ h,
                                           unsigned short* wbuf,    // 2*4096 shorts
                                           unsigned short* ou) {    // 4*1024 shorts
    int wv = tid >> 6, lane = tid & 63;
    int m = lane & 15, q = lane >> 4;
    int nb = tile * 64 + wv * 16;
    bool active = (nb < N_NODES);
    int n = active ? (nb + m) : 0;

    const float* xr = x + (size_t)n * 64 + q * 8;
    float4 x0a = *(const float4*)(xr);
    float4 x0b = *(const float4*)(xr + 4);
    float4 x1a = *(const float4*)(xr + 32);
    float4 x1b = *(const float4*)(xr + 36);
    s8v b0, b1;
    b0[0] = f2bf(x0a.x); b0[1] = f2bf(x0a.y); b0[2] = f2bf(x0a.z); b0[3] = f2bf(x0a.w);
    b0[4] = f2bf(x0b.x); b0[5] = f2bf(x0b.y); b0[6] = f2bf(x0b.z); b0[7] = f2bf(x0b.w);
    b1[0] = f2bf(x1a.x); b1[1] = f2bf(x1a.y); b1[2] = f2bf(x1a.z); b1[3] = f2bf(x1a.w);
    b1[4] = f2bf(x1b.x); b1[5] = f2bf(x1b.y); b1[6] = f2bf(x1b.z); b1[7] = f2bf(x1b.w);

    int c0 = tid, c1 = tid + 256;
    int p0s = (c0 >> 3) * 64 + (((c0 & 7) ^ ((c0 >> 3) & 7)) << 3);
    int p1s = (c1 >> 3) * 64 + (((c1 & 7) ^ ((c1 >> 3) & 7)) << 3);

    {
        const int4* src = (const int4*)w1T;
        int4 v0 = src[c0], v1 = src[c1];
        *(int4*)&wbuf[p0s] = v0;
        *(int4*)&wbuf[p1s] = v1;
    }
    __syncthreads();

    for (int w = 0; w < 17; w++) {
        int cur = w & 1;
        if (w < 16) {
            const int4* src = (const int4*)w1T + (w + 1) * 512;
            int4 v0 = src[c0], v1 = src[c1];
            *(int4*)&wbuf[(cur ^ 1) * 4096 + p0s] = v0;
            *(int4*)&wbuf[(cur ^ 1) * 4096 + p1s] = v1;
        }
        #pragma unroll
        for (int ct = 0; ct < 4; ct++) {
            int ro = ct * 16 + m;
            int pa = q ^ (ro & 7);
            int pb = (4 + q) ^ (ro & 7);
            s8v A0 = *(const s8v*)&wbuf[cur * 4096 + ro * 64 + pa * 8];
            s8v A1 = *(const s8v*)&wbuf[cur * 4096 + ro * 64 + pb * 8];
            f4v acc = (f4v){0.f, 0.f, 0.f, 0.f};
            acc = __builtin_amdgcn_mfma_f32_16x16x32_bf16(A0, b0, acc, 0, 0, 0);
            acc = __builtin_amdgcn_mfma_f32_16x16x32_bf16(A1, b1, acc, 0, 0, 0);
            ushort4 o4;
            o4.x = f2bf(acc[0]); o4.y = f2bf(acc[1]); o4.z = f2bf(acc[2]); o4.w = f2bf(acc[3]);
            int g = ct * 2 + (q >> 1);
            int pg = g ^ (m & 7);
            *(ushort4*)&ou[wv * 1024 + m * 64 + pg * 8 + (q & 1) * 4] = o4;
        }
        if (active) {
            int r1 = lane >> 3, g1 = lane & 7;
            int pg1 = g1 ^ (r1 & 7);
            int4 d0 = *(const int4*)&ou[wv * 1024 + r1 * 64 + pg1 * 8];
            int4 d1 = *(const int4*)&ou[wv * 1024 + (r1 + 8) * 64 + pg1 * 8];
            unsigned short* base = (w < 16) ? (t1 + ((size_t)w * N_NODES + nb) * 64)
                                            : (h + (size_t)nb * 64);
            *(int4*)(base + lane * 8) = d0;
            *(int4*)(base + 512 + lane * 8) = d1;
        }
        __syncthreads();
    }
}

// ---- FUSED: gemm1 (blocks 0..781) || bucket scatter (rest) — R13-proven ----
__global__ __launch_bounds__(256) void k_fused1(const float* __restrict__ x,
                                                const unsigned short* __restrict__ w1T,
                                                unsigned short* __restrict__ t1,
                                                unsigned short* __restrict__ h,
                                                const int* __restrict__ ei,
                                                const int* __restrict__ et,
                                                int* __restrict__ cursor,
                                                int* __restrict__ sed) {
    __shared__ __align__(16) unsigned short wbuf[2 * 4096];
    __shared__ __align__(16) unsigned short ou[4 * 1024];
    if (blockIdx.x >= G1_BLOCKS) {
        int e = (blockIdx.x - G1_BLOCKS) * 256 + threadIdx.x;
        if (e < N_EDGES) {
            int src = ei[e];
            int dst = ei[N_EDGES + e];
            int t = et[e];
            int pos = atomicAdd(&cursor[dst], 1);
            if (pos < CAP) sed[dst * CAP + pos] = (t << 16) | src;
        }
        return;
    }
    gemm1_tile(blockIdx.x, threadIdx.x, x, w1T, t1, h, wbuf, ou);
}

// ---- FUSED agg1 + relu + gemm2: block = 16 nodes ----
// Phase 1 (barrier-free): 16 lanes/node (slot=sub>>3, d8=sub&7), 2 slots x unroll-2,
//   slot-parallel gather of t1 rows + LDS hist for inv; reduce; +self(h); relu -> htile LDS.
// Phase 2 (after 1 barrier): 17 MFMAs on the 16-node tile, A from w2T (L2-hot),
//   waves split weights (4 each + wave0 does self->out). Stores t2 (bf16) + out (fp32).
__global__ __launch_bounds__(256) void k_aggt(const int* __restrict__ cursor,
                                              const int* __restrict__ sed,
                                              const unsigned short* __restrict__ t1,
                                              const unsigned short* __restrict__ h,
                                              const unsigned short* __restrict__ w2T,
                                              unsigned short* __restrict__ t2,
                                              float* __restrict__ out) {
    __shared__ int hist[16][16];
    __shared__ __align__(16) unsigned short htile[16][72];   // stride 72: 16B-aligned rows, 2-way banks
    int tid = threadIdx.x;
    int nb = blockIdx.x * 16;          // 3125*16 = 50000 exact
    int j = tid >> 4;                  // node in block
    int sub = tid & 15;
    int n = nb + j;
    int deg = cursor[n];
    deg = deg < CAP ? deg : CAP;
    const int* bucket = sed + n * CAP;

    // ---- phase 1: all LDS state is 16-lane-group-local -> wave-internal ordering, no barriers
    hist[j][sub] = 0;
    for (int i = sub; i < deg; i += 16)
        atomicAdd(&hist[j][bucket[i] >> 16], 1);

    int slot = sub >> 3;      // 0..1
    int d8 = sub & 7;         // dim group: 8 bf16
    float a[8];
    #pragma unroll
    for (int k = 0; k < 8; k++) a[k] = 0.f;
    for (int i = slot; i < deg; i += 4) {     // slot0: 0,2|4,6..  slot1: 1,3|5,7..
        int e0 = bucket[i];
        bool has1 = (i + 2) < deg;
        int e1 = has1 ? bucket[i + 2] : e0;
        int t0 = e0 >> 16, s0 = e0 & 0xFFFF;
        int t1i = e1 >> 16, s1 = e1 & 0xFFFF;
        float inv0 = 1.0f / (float)hist[j][t0];
        float inv1 = has1 ? (1.0f / (float)hist[j][t1i]) : 0.f;
        int4 p0 = *(const int4*)(t1 + ((size_t)(t0 * N_NODES + s0)) * 64 + d8 * 8);
        int4 p1 = *(const int4*)(t1 + ((size_t)(t1i * N_NODES + s1)) * 64 + d8 * 8);
        acc8(a, inv0, p0);
        acc8(a, inv1, p1);
    }
    #pragma unroll
    for (int k = 0; k < 8; k++) a[k] += __shfl_xor(a[k], 8, 64);   // merge 2 slots
    if (slot == 0) {
        int4 hs = *(const int4*)(h + (size_t)n * 64 + d8 * 8);     // self term
        acc8(a, 1.0f, hs);
        ushort4 lo, hi;
        lo.x = f2bf(a[0] > 0.f ? a[0] : 0.f);
        lo.y = f2bf(a[1] > 0.f ? a[1] : 0.f);
        lo.z = f2bf(a[2] > 0.f ? a[2] : 0.f);
        lo.w = f2bf(a[3] > 0.f ? a[3] : 0.f);
        hi.x = f2bf(a[4] > 0.f ? a[4] : 0.f);
        hi.y = f2bf(a[5] > 0.f ? a[5] : 0.f);
        hi.z = f2bf(a[6] > 0.f ? a[6] : 0.f);
        hi.w = f2bf(a[7] > 0.f ? a[7] : 0.f);
        *(ushort4*)&htile[j][d8 * 8] = lo;
        *(ushort4*)&htile[j][d8 * 8 + 4] = hi;
    }
    __syncthreads();

    // ---- phase 2: MFMA transform of the 16-node tile
    int wv = tid >> 6, lane = tid & 63;
    int m = lane & 15, q = lane >> 4;
    int nn = nb + m;
    s8v b0 = *(const s8v*)&htile[m][q * 8];
    s8v b1 = *(const s8v*)&htile[m][32 + q * 8];
    const unsigned short* wp = w2T + m * 64 + q * 8;

    #pragma unroll
    for (int j5 = 0; j5 < 4; j5++) {
        int w = wv * 4 + j5;
        s8v A0 = *(const s8v*)(wp + (w << 10));
        s8v A1 = *(const s8v*)(wp + (w << 10) + 32);
        f4v acc = (f4v){0.f, 0.f, 0.f, 0.f};
        acc = __builtin_amdgcn_mfma_f32_16x16x32_bf16(A0, b0, acc, 0, 0, 0);
        acc = __builtin_amdgcn_mfma_f32_16x16x32_bf16(A1, b1, acc, 0, 0, 0);
        ushort4 o;
        o.x = f2bf(acc[0]); o.y = f2bf(acc[1]); o.z = f2bf(acc[2]); o.w = f2bf(acc[3]);
        *(ushort4*)(t2 + ((size_t)w * N_NODES + nn) * 16 + q * 4) = o;
    }
    if (wv == 0) {    // self slot -> out (fp32)
        s8v A0 = *(const s8v*)(wp + (16 << 10));
        s8v A1 = *(const s8v*)(wp + (16 << 10) + 32);
        f4v acc = (f4v){0.f, 0.f, 0.f, 0.f};
        acc = __builtin_amdgcn_mfma_f32_16x16x32_bf16(A0, b0, acc, 0, 0, 0);
        acc = __builtin_amdgcn_mfma_f32_16x16x32_bf16(A1, b1, acc, 0, 0, 0);
        *(float4*)(out + (size_t)nn * 16 + q * 4) = make_float4(acc[0], acc[1], acc[2], acc[3]);
    }
}

// ---- layer-2 aggregation (R13-proven): 16 lanes/node, 8 slots x unroll-2, LDS hist ----
__global__ __launch_bounds__(256) void k_agg2(const int* __restrict__ cursor,
                                              const int* __restrict__ sed,
                                              const unsigned short* __restrict__ t2,
                                              float* __restrict__ out) {
    __shared__ int hist[16][16];
    int tid = threadIdx.x;
    int j = tid >> 4;          // node in block 0..15
    int sub = tid & 15;
    int n = blockIdx.x * 16 + j;   // 3125*16 = 50000 exact
    int deg = cursor[n];
    deg = deg < CAP ? deg : CAP;
    const int* bucket = sed + n * CAP;

    hist[j][sub] = 0;
    for (int i = sub; i < deg; i += 16)
        atomicAdd(&hist[j][bucket[i] >> 16], 1);
    // 16-lane-group-local LDS, wave-internal ordering: no barrier needed

    int slot = sub >> 1;       // edge slot 0..7
    int d2 = sub & 1;          // dim half: 8 bf16
    float a[8];
    #pragma unroll
    for (int k = 0; k < 8; k++) a[k] = 0.f;
    for (int i = slot; i < deg; i += 16) {
        int e0 = bucket[i];
        bool has1 = (i + 8) < deg;
        int e1 = has1 ? bucket[i + 8] : e0;
        int t0 = e0 >> 16, s0 = e0 & 0xFFFF;
        int t1i = e1 >> 16, s1 = e1 & 0xFFFF;
        float inv0 = 1.0f / (float)hist[j][t0];
        float inv1 = has1 ? (1.0f / (float)hist[j][t1i]) : 0.f;
        int4 p0 = *(const int4*)(t2 + ((size_t)(t0 * N_NODES + s0)) * 16 + d2 * 8);
        int4 p1 = *(const int4*)(t2 + ((size_t)(t1i * N_NODES + s1)) * 16 + d2 * 8);
        acc8(a, inv0, p0);
        acc8(a, inv1, p1);
    }
    #pragma unroll
    for (int k = 0; k < 8; k++) {
        a[k] += __shfl_xor(a[k], 2, 64);
        a[k] += __shfl_xor(a[k], 4, 64);
        a[k] += __shfl_xor(a[k], 8, 64);
    }
    if (slot == 0) {
        float* p = out + (size_t)n * 16 + d2 * 8;
        float4 c0 = *(const float4*)p;
        float4 c1 = *(const float4*)(p + 4);
        c0.x += a[0]; c0.y += a[1]; c0.z += a[2]; c0.w += a[3];
        c1.x += a[4]; c1.y += a[5]; c1.z += a[6]; c1.w += a[7];
        *(float4*)p = c0;
        *(float4*)(p + 4) = c1;
    }
}

extern "C" void kernel_launch(void* const* d_in, const int* in_sizes, int n_in,
                              void* d_out, int out_size, void* d_ws, size_t ws_size,
                              hipStream_t stream) {
    const float* x      = (const float*)d_in[0];
    const float* bases1 = (const float*)d_in[1];
    const float* coeffs1= (const float*)d_in[2];
    const float* self1  = (const float*)d_in[3];
    const float* bases2 = (const float*)d_in[4];
    const float* coeffs2= (const float*)d_in[5];
    const float* self2  = (const float*)d_in[6];
    const int*   ei     = (const int*)d_in[7];
    const int*   et     = (const int*)d_in[8];
    float* out = (float*)d_out;

    char* ws = (char*)d_ws;
    int*            cursor = (int*)(ws + 0);                    //     200,064
    unsigned short* w1T    = (unsigned short*)(ws + 200064);    //     139,264
    unsigned short* w2T    = (unsigned short*)(ws + 339328);    //      34,816
    int*            sed    = (int*)(ws + 374144);               //  12,800,000 (50000 x 64 x 4B)
    unsigned short* h      = (unsigned short*)(ws + 13174144);  //   6,400,000
    unsigned short* t1     = (unsigned short*)(ws + 19574144);  // 102,400,000 -> 121,974,144
    unsigned short* t2     = (unsigned short*)(ws + 121974144); //  25,600,000 -> 147,574,144

    k_pre<<<WREL_BLOCKS + ZERO_BLOCKS, 256, 0, stream>>>(
        bases1, coeffs1, self1, bases2, coeffs2, self2, w1T, w2T, cursor);
    k_fused1<<<G1_BLOCKS + SC_BLOCKS, 256, 0, stream>>>(x, w1T, t1, h, ei, et, cursor, sed);
    k_aggt<<<SC_BLOCKS, 256, 0, stream>>>(cursor, sed, t1, h, w2T, t2, out);
    k_agg2<<<SC_BLOCKS, 256, 0, stream>>>(cursor, sed, t2, out);
}